// Round 11
// baseline (37750.662 us; speedup 1.0000x reference)
//
#include <hip/hip_runtime.h>

#define DEV __device__ __forceinline__

namespace {
constexpr int Bc = 32;
constexpr int Tc = 256;
constexpr int Dc = 512;
constexpr int NBLK = 256;
constexpr int NW   = 128;          // writer blocks (own 16 mem rows each)
constexpr int ROWS = 16;
constexpr int NT   = 512;          // threads per k_main block (8 waves)

// rp: [2][NW][B][Dc/4] u64 packets, each = 4 bf16 cols
constexpr size_t RPPAR64 = (size_t)NW * Bc * (Dc / 4);   // u64s per parity

// workspace layout (float offsets)
constexpr size_t OFF_KN   = 0;                                  // [T][B][D] normalized k
constexpr size_t OFF_E    = OFF_KN + (size_t)Tc * Bc * Dc;      // [T][B][D] sigmoid(erase)
constexpr size_t OFF_A    = OFF_E  + (size_t)Tc * Bc * Dc;      // [T][B][D] add
constexpr size_t OFF_RP   = OFF_A  + (size_t)Tc * Bc * Dc;      // 2*RPPAR64 u64s
constexpr size_t OFF_DENP = OFF_RP + 2 * RPPAR64 * 2;           // [2][NW][B] den partials
constexpr size_t OFF_FLAGS= OFF_DENP + (size_t)2 * NW * Bc;     // 256*16 u32 arrival flags
}

DEV float sigm(float x) { return 1.0f / (1.0f + __expf(-x)); }

// Agent-scope relaxed helpers (proven coherent across XCDs, R3-R10).
DEV float ld1cg(const float* p) {
  unsigned u = __hip_atomic_load((const unsigned*)p, __ATOMIC_RELAXED,
                                 __HIP_MEMORY_SCOPE_AGENT);
  return __uint_as_float(u);
}
DEV void st1cg(float* p, float v) {
  __hip_atomic_store((unsigned*)p, __float_as_uint(v), __ATOMIC_RELAXED,
                     __HIP_MEMORY_SCOPE_AGENT);
}
DEV unsigned long long ld8cg(const unsigned long long* p) {
  return __hip_atomic_load(p, __ATOMIC_RELAXED, __HIP_MEMORY_SCOPE_AGENT);
}
DEV void st8cg(unsigned long long* p, unsigned long long v) {
  __hip_atomic_store(p, v, __ATOMIC_RELAXED, __HIP_MEMORY_SCOPE_AGENT);
}

DEV unsigned pack_bf2(float x, float y) {   // RNE f32->bf16 pair (R8-proven)
  unsigned ux = __float_as_uint(x), uy = __float_as_uint(y);
  unsigned rx = (ux + 0x7FFFu + ((ux >> 16) & 1u)) >> 16;
  unsigned ry = (uy + 0x7FFFu + ((uy >> 16) & 1u)) >> 16;
  return rx | (ry << 16);
}
DEV float lo16f(unsigned u) { return __uint_as_float(u << 16); }
DEV float hi16f(unsigned u) { return __uint_as_float(u & 0xFFFF0000u); }

// ---------------------------------------------------------------------------
// K1: 4 fused controller GEMMs (unchanged, validated).
// ---------------------------------------------------------------------------
__global__ __launch_bounds__(256) void k_gemm(
    const float* __restrict__ A,
    const float* __restrict__ Wk, const float* __restrict__ bk,
    const float* __restrict__ We, const float* __restrict__ be,
    const float* __restrict__ Ww, const float* __restrict__ bw,
    const float* __restrict__ Wg, const float* __restrict__ bg,
    float* __restrict__ ws, float* __restrict__ gout)
{
  __shared__ float As[32][68];
  __shared__ float Bs[32][68];

  const int bid = blockIdx.x;
  const int mat = bid >> 10;
  const int rem = bid & 1023;
  const int rt = rem >> 3, jt = rem & 7;
  const int rbase = rt * 64, jbase = jt * 64;

  const float* Wm; const float* bm;
  if      (mat == 0) { Wm = Wk; bm = bk; }
  else if (mat == 1) { Wm = We; bm = be; }
  else if (mat == 2) { Wm = Ww; bm = bw; }
  else               { Wm = Wg; bm = bg; }

  const int tid = threadIdx.x;
  const int lr = tid >> 2;
  const int lk = (tid & 3) * 8;
  const int ty = tid >> 4, tx = tid & 15;

  float acc[4][4] = {};

  for (int k0 = 0; k0 < Dc; k0 += 32) {
    const float4 a0 = *(const float4*)&A [(size_t)(rbase + lr) * Dc + k0 + lk];
    const float4 a1 = *(const float4*)&A [(size_t)(rbase + lr) * Dc + k0 + lk + 4];
    const float4 b0 = *(const float4*)&Wm[(size_t)(jbase + lr) * Dc + k0 + lk];
    const float4 b1 = *(const float4*)&Wm[(size_t)(jbase + lr) * Dc + k0 + lk + 4];
    __syncthreads();
    As[lk + 0][lr] = a0.x; As[lk + 1][lr] = a0.y; As[lk + 2][lr] = a0.z; As[lk + 3][lr] = a0.w;
    As[lk + 4][lr] = a1.x; As[lk + 5][lr] = a1.y; As[lk + 6][lr] = a1.z; As[lk + 7][lr] = a1.w;
    Bs[lk + 0][lr] = b0.x; Bs[lk + 1][lr] = b0.y; Bs[lk + 2][lr] = b0.z; Bs[lk + 3][lr] = b0.w;
    Bs[lk + 4][lr] = b1.x; Bs[lk + 5][lr] = b1.y; Bs[lk + 6][lr] = b1.z; Bs[lk + 7][lr] = b1.w;
    __syncthreads();
    #pragma unroll
    for (int kk = 0; kk < 32; ++kk) {
      const float4 av = *(const float4*)&As[kk][ty * 4];
      const float4 bv = *(const float4*)&Bs[kk][tx * 4];
      const float ar[4] = {av.x, av.y, av.z, av.w};
      const float br[4] = {bv.x, bv.y, bv.z, bv.w};
      #pragma unroll
      for (int i = 0; i < 4; ++i)
        #pragma unroll
        for (int j = 0; j < 4; ++j)
          acc[i][j] = fmaf(ar[i], br[j], acc[i][j]);
    }
  }

  const float4 bias = *(const float4*)&bm[jbase + tx * 4];
  const float bi[4] = {bias.x, bias.y, bias.z, bias.w};
  #pragma unroll
  for (int i = 0; i < 4; ++i) {
    const int r = rbase + ty * 4 + i;
    float v[4];
    #pragma unroll
    for (int j = 0; j < 4; ++j) {
      v[j] = acc[i][j] + bi[j];
      if (mat & 1) v[j] = sigm(v[j]);
    }
    float4 o; o.x = v[0]; o.y = v[1]; o.z = v[2]; o.w = v[3];
    if (mat == 3) {
      *(float4*)&gout[(size_t)r * Dc + jbase + tx * 4] = o;   // g -> d_out (temp)
    } else {
      float* dst = ws + (mat == 0 ? OFF_KN : (mat == 1 ? OFF_E : OFF_A));
      const int t = r & 255, b = r >> 8;                      // r = b*T + t
      *(float4*)&dst[((size_t)t * Bc + b) * Dc + jbase + tx * 4] = o;
    }
  }
}

// ---------------------------------------------------------------------------
// K2: l2-normalize k rows in place (unchanged).
// ---------------------------------------------------------------------------
__global__ __launch_bounds__(256) void k_knorm(float* __restrict__ kn)
{
  const int row = blockIdx.x * 4 + (threadIdx.x >> 6);
  const int lane = threadIdx.x & 63;
  float* p = kn + (size_t)row * Dc;
  float4 v0 = *(const float4*)&p[lane * 4];
  float4 v1 = *(const float4*)&p[256 + lane * 4];
  float ss = v0.x*v0.x + v0.y*v0.y + v0.z*v0.z + v0.w*v0.w
           + v1.x*v1.x + v1.y*v1.y + v1.z*v1.z + v1.w*v1.w;
  #pragma unroll
  for (int off = 32; off >= 1; off >>= 1) ss += __shfl_xor(ss, off);
  const float inv = 1.0f / fmaxf(sqrtf(ss), 1e-12f);
  v0.x *= inv; v0.y *= inv; v0.z *= inv; v0.w *= inv;
  v1.x *= inv; v1.y *= inv; v1.z *= inv; v1.w *= inv;
  *(float4*)&p[lane * 4] = v0;
  *(float4*)&p[256 + lane * 4] = v1;
}

// ---------------------------------------------------------------------------
// Single-hop all-to-all barrier; threads 0..255 poll one flag each (proven).
// ---------------------------------------------------------------------------
DEV void gbar(unsigned* flags, unsigned step, int bid, int tid)
{
  __syncthreads();                 // drains vmcnt per wave -> stores coherent
  if (tid == 0)
    __hip_atomic_store(&flags[bid * 16], step, __ATOMIC_RELAXED,
                       __HIP_MEMORY_SCOPE_AGENT);
  if (tid < 256) {
    while (__hip_atomic_load(&flags[tid * 16], __ATOMIC_RELAXED,
                             __HIP_MEMORY_SCOPE_AGENT) < step)
      __builtin_amdgcn_s_sleep(1);
  }
  __syncthreads();
}

// ---------------------------------------------------------------------------
// sim phase (512t): thread = (row r = tid>>5, batch bp = tid&31).
// ---------------------------------------------------------------------------
DEV void sim_phase(const float* __restrict__ knp, float* __restrict__ denp_row,
                   const float (*y)[516], float* __restrict__ ew_own,
                   const float* invn_s, int tid)
{
  const int r = tid >> 5, bp = tid & 31;
  const float* kp = knp + (size_t)bp * Dc;
  float acc = 0.f;
  #pragma unroll 4
  for (int dq = 0; dq < Dc / 4; ++dq) {
    const float4 y4 = *(const float4*)&y[r][dq * 4];
    const float4 k4 = *(const float4*)&kp[dq * 4];
    acc = fmaf(y4.x, k4.x, acc); acc = fmaf(y4.y, k4.y, acc);
    acc = fmaf(y4.z, k4.z, acc); acc = fmaf(y4.w, k4.w, acc);
  }
  ew_own[tid] = __expf(acc * invn_s[r]);   // layout [r][bp] == tid
  __syncthreads();
  if (tid < 32) {
    float s = 0.f;
    #pragma unroll
    for (int r2 = 0; r2 < 16; ++r2) s += ew_own[r2 * 32 + tid];
    st1cg(&denp_row[tid], s);
  }
}

// ---------------------------------------------------------------------------
// Persistent recurrent kernel: 256 blocks x 512 threads (2 waves/SIMD).
// rp transport: bf16x4 u64 packets, register-packed via shfl (no LDS bounce).
// ---------------------------------------------------------------------------
__global__ __launch_bounds__(NT) void k_main(
    const float* __restrict__ cs, const float* __restrict__ mem_in,
    const float* __restrict__ gamma, const float* __restrict__ beta,
    float* __restrict__ ws, float* __restrict__ out)
{
  __shared__ float mrows[16][516];   // persistent memory rows (W)
  __shared__ float ew_own[512];      // [r][bp] exp(sim) at current t (W)
  __shared__ float wbuf[16][32];
  __shared__ float lds_red[512];     // den agg (W)
  __shared__ float redR[16][128];    // reducer col reduce
  __shared__ float mu_s[16], rs_s[16], invn_s[16], dinv_s[32];

  float* kn   = ws + OFF_KN;
  float* eptb = ws + OFF_E;
  float* aptb = ws + OFF_A;
  unsigned long long* rp64_all = (unsigned long long*)(ws + OFF_RP);
  float* denp = ws + OFF_DENP;
  unsigned* flags = (unsigned*)(ws + OFF_FLAGS);

  const int bid = blockIdx.x, tid = threadIdx.x;
  const float inv32 = 1.0f / 32.0f;

  float ev[32], av[32];                       // e[t]/a[t] resident (W)
  const float gmv = gamma[tid & 511];
  const float btv = beta[tid & 511];

  if (bid < NW) {
    const int s0 = bid * ROWS;
    #pragma unroll
    for (int r = 0; r < ROWS; ++r)
      mrows[r][tid] = mem_in[(size_t)(s0 + r) * Dc + tid];
    #pragma unroll
    for (int b = 0; b < 32; ++b) {
      ev[b] = eptb[(size_t)b * Dc + tid];
      av[b] = aptb[(size_t)b * Dc + tid];
    }
    __syncthreads();
    {
      const int row = tid >> 5, li = tid & 31;
      float ss = 0.f;
      #pragma unroll
      for (int i = 0; i < 4; ++i) {
        const float4 v = *(const float4*)&mrows[row][(li + i * 32) * 4];
        ss += v.x*v.x + v.y*v.y + v.z*v.z + v.w*v.w;
      }
      ss += __shfl_xor(ss, 16); ss += __shfl_xor(ss, 8);
      ss += __shfl_xor(ss, 4);  ss += __shfl_xor(ss, 2);
      ss += __shfl_xor(ss, 1);
      if (li == 0) invn_s[row] = 1.0f / fmaxf(sqrtf(ss), 1e-12f);
    }
    __syncthreads();
    sim_phase(kn, denp + (size_t)bid * Bc, mrows, ew_own, invn_s, tid);
  }
  gbar(flags, 1u, bid, tid);

  for (int t = 0; t <= Tc; ++t) {
    if (bid < NW) {
      if (t < Tc) {
        // 1) den agg from 128 partials (parity t&1): 8 loads/thread (proven)
        {
          const float* dp = denp + (size_t)(t & 1) * NW * Bc;
          const int ch = tid >> 5, b = tid & 31;
          float s = 0.f;
          #pragma unroll
          for (int g = 0; g < 8; ++g)
            s += ld1cg(&dp[(size_t)(ch * 8 + g) * Bc + b]);
          lds_red[tid] = s;
          __syncthreads();
          if (tid < 32) {
            float tot = 0.f;
            #pragma unroll
            for (int c2 = 0; c2 < 16; ++c2) tot += lds_red[c2 * 32 + tid];
            dinv_s[tid] = 1.0f / tot;
          }
          __syncthreads();
        }
        // 2) normalized weights (one entry per thread)
        wbuf[tid >> 5][tid & 31] = ew_own[tid] * dinv_s[tid & 31];
        __syncthreads();

        float mr[16];
        #pragma unroll
        for (int r = 0; r < ROWS; ++r) mr[r] = mrows[r][tid];

        // 3a) rp pass; pack bf16x4 via shfl; 8 u64 stores/thread
        {
          float rpv[32] = {};
          #pragma unroll
          for (int r = 0; r < ROWS; ++r) {
            const float mrr = mr[r];
            #pragma unroll
            for (int b4 = 0; b4 < 8; ++b4) {
              const float4 w4 = *(const float4*)&wbuf[r][b4 * 4];
              rpv[b4*4+0] = fmaf(w4.x, mrr, rpv[b4*4+0]);
              rpv[b4*4+1] = fmaf(w4.y, mrr, rpv[b4*4+1]);
              rpv[b4*4+2] = fmaf(w4.z, mrr, rpv[b4*4+2]);
              rpv[b4*4+3] = fmaf(w4.w, mrr, rpv[b4*4+3]);
            }
          }
          unsigned long long* rp64 = rp64_all + (size_t)(t & 1) * RPPAR64
                                   + (size_t)bid * Bc * (Dc / 4);
          const int lsel = tid & 3;
          const int cu = tid >> 2;               // u64 column 0..127
          #pragma unroll
          for (int b = 0; b < 32; ++b) {
            const float o = __shfl_xor(rpv[b], 1);
            const unsigned wv = (tid & 1) ? pack_bf2(o, rpv[b])
                                          : pack_bf2(rpv[b], o);
            const unsigned wx = (unsigned)__shfl_xor((int)wv, 2);
            const unsigned lo = (tid & 2) ? wx : wv;
            const unsigned hi = (tid & 2) ? wv : wx;
            if (lsel == (b & 3))
              st8cg(&rp64[(size_t)b * (Dc / 4) + cu],
                    (unsigned long long)lo | ((unsigned long long)hi << 32));
          }
        }

        if (t < Tc - 1) {
          // 3b) erase/add pass
          float er[16] = {}, ad[16] = {};
          #pragma unroll
          for (int r = 0; r < ROWS; ++r) {
            #pragma unroll
            for (int b4 = 0; b4 < 8; ++b4) {
              const float4 w4 = *(const float4*)&wbuf[r][b4 * 4];
              er[r] = fmaf(w4.x, ev[b4*4+0], er[r]);
              er[r] = fmaf(w4.y, ev[b4*4+1], er[r]);
              er[r] = fmaf(w4.z, ev[b4*4+2], er[r]);
              er[r] = fmaf(w4.w, ev[b4*4+3], er[r]);
              ad[r] = fmaf(w4.x, av[b4*4+0], ad[r]);
              ad[r] = fmaf(w4.y, av[b4*4+1], ad[r]);
              ad[r] = fmaf(w4.z, av[b4*4+2], ad[r]);
              ad[r] = fmaf(w4.w, av[b4*4+3], ad[r]);
            }
          }
          // 4) x = m*(1-er/32) + ad/32, staged to mrows
          float xr[16];
          #pragma unroll
          for (int r = 0; r < ROWS; ++r) {
            const float x = mr[r] * (1.0f - er[r] * inv32) + ad[r] * inv32;
            xr[r] = x;
            mrows[r][tid] = x;
          }
          // 5) prefetch e/a for t+1
          if (t <= Tc - 3) {
            const float* ep1 = eptb + (size_t)(t + 1) * Bc * Dc;
            const float* ap1 = aptb + (size_t)(t + 1) * Bc * Dc;
            #pragma unroll
            for (int b = 0; b < 32; ++b) {
              ev[b] = ep1[(size_t)b * Dc + tid];
              av[b] = ap1[(size_t)b * Dc + tid];
            }
          }
          __syncthreads();
          // 6) LN stats
          {
            const int row = tid >> 5, li = tid & 31;
            float s1 = 0.f, s2 = 0.f;
            #pragma unroll
            for (int i = 0; i < 4; ++i) {
              const float4 v = *(const float4*)&mrows[row][(li + i * 32) * 4];
              s1 += v.x + v.y + v.z + v.w;
              s2 += v.x*v.x + v.y*v.y + v.z*v.z + v.w*v.w;
            }
            s1 += __shfl_xor(s1, 16); s2 += __shfl_xor(s2, 16);
            s1 += __shfl_xor(s1, 8);  s2 += __shfl_xor(s2, 8);
            s1 += __shfl_xor(s1, 4);  s2 += __shfl_xor(s2, 4);
            s1 += __shfl_xor(s1, 2);  s2 += __shfl_xor(s2, 2);
            s1 += __shfl_xor(s1, 1);  s2 += __shfl_xor(s2, 1);
            if (li == 0) {
              const float mu = s1 * (1.0f / 512.0f);
              const float var = s2 * (1.0f / 512.0f) - mu * mu;
              mu_s[row] = mu;
              rs_s[row] = rsqrtf(var + 1e-5f);
            }
          }
          __syncthreads();
          // 7) apply LN into mrows
          #pragma unroll
          for (int r = 0; r < ROWS; ++r) {
            const float y = (xr[r] - mu_s[r]) * rs_s[r] * gmv + btv;
            mrows[r][tid] = y;
          }
          __syncthreads();
          // 8) row l2 norms
          {
            const int row = tid >> 5, li = tid & 31;
            float ss = 0.f;
            #pragma unroll
            for (int i = 0; i < 4; ++i) {
              const float4 v = *(const float4*)&mrows[row][(li + i * 32) * 4];
              ss += v.x*v.x + v.y*v.y + v.z*v.z + v.w*v.w;
            }
            ss += __shfl_xor(ss, 16); ss += __shfl_xor(ss, 8);
            ss += __shfl_xor(ss, 4);  ss += __shfl_xor(ss, 2);
            ss += __shfl_xor(ss, 1);
            if (li == 0) invn_s[row] = 1.0f / fmaxf(sqrtf(ss), 1e-12f);
          }
          __syncthreads();
          // 9) sim for t+1
          sim_phase(kn + (size_t)(t + 1) * Bc * Dc,
                    denp + (size_t)((t + 1) & 1) * NW * Bc + (size_t)bid * Bc,
                    mrows, ew_own, invn_s, tid);
        }
      }
    } else {
      // Reducer: out for step t-1 from bf16x4 packed rp.
      if (t >= 1) {
        const int t0 = t - 1;
        const int rb = bid - NW;
        const int b = rb >> 2;
        const int d0 = (rb & 3) * 128;
        const unsigned long long* rpc = rp64_all + (size_t)(t0 & 1) * RPPAR64;
        const int pg = tid >> 5;           // 0..15: group of 8 partials
        const int cu = tid & 31;           // u64 within the 128-col slice
        const size_t cofs = (size_t)(d0 / 4) + cu;
        float acc[4] = {};
        #pragma unroll
        for (int i = 0; i < 8; ++i) {
          const int p = pg * 8 + i;
          const unsigned long long v =
              ld8cg(&rpc[((size_t)p * Bc + b) * (Dc / 4) + cofs]);
          const unsigned u0 = (unsigned)v, u1 = (unsigned)(v >> 32);
          acc[0] += lo16f(u0); acc[1] += hi16f(u0);
          acc[2] += lo16f(u1); acc[3] += hi16f(u1);
        }
        #pragma unroll
        for (int j = 0; j < 4; ++j) redR[pg][cu * 4 + j] = acc[j];
        __syncthreads();
        if (tid < 128) {
          float s = 0.f;
          #pragma unroll
          for (int p = 0; p < 16; ++p) s += redR[p][tid];
          const size_t oofs = ((size_t)b * Tc + t0) * Dc + d0 + tid;
          const float g  = out[oofs];
          const float cv = cs[oofs];
          out[oofs] = g * cv + (1.0f - g) * s;
        }
        __syncthreads();
      }
    }
    if (t < Tc) gbar(flags, (unsigned)(t + 2), bid, tid);
  }
}

// ---------------------------------------------------------------------------
extern "C" void kernel_launch(void* const* d_in, const int* in_sizes, int n_in,
                              void* d_out, int out_size, void* d_ws, size_t ws_size,
                              hipStream_t stream)
{
  const float* cs    = (const float*)d_in[0];
  const float* mem   = (const float*)d_in[1];
  const float* Wk    = (const float*)d_in[2];
  const float* bk    = (const float*)d_in[3];
  const float* We    = (const float*)d_in[4];
  const float* be    = (const float*)d_in[5];
  const float* Ww    = (const float*)d_in[6];
  const float* bw    = (const float*)d_in[7];
  const float* Wg    = (const float*)d_in[8];
  const float* bg    = (const float*)d_in[9];
  const float* gamma = (const float*)d_in[10];
  const float* beta  = (const float*)d_in[11];
  float* ws  = (float*)d_ws;
  float* out = (float*)d_out;

  // zero barrier flags
  hipMemsetAsync(ws + OFF_FLAGS, 0, 256 * 16 * sizeof(unsigned), stream);

  hipLaunchKernelGGL(k_gemm, dim3(4096), dim3(256), 0, stream,
                     cs, Wk, bk, We, be, Ww, bw, Wg, bg, ws, out);
  hipLaunchKernelGGL(k_knorm, dim3(2048), dim3(256), 0, stream, ws + OFF_KN);
  hipLaunchKernelGGL(k_main, dim3(NBLK), dim3(NT), 0, stream,
                     cs, mem, gamma, beta, ws, out);
}

// Round 12
// 11540.683 us; speedup vs baseline: 3.2711x; 3.2711x over previous
//
#include <hip/hip_runtime.h>

#define DEV __device__ __forceinline__

namespace {
constexpr int Bc = 32;
constexpr int Tc = 256;
constexpr int Dc = 512;
constexpr int NBLK = 256;
constexpr int NW   = 128;          // writer blocks (own 16 mem rows each)
constexpr int ROWS = 16;
constexpr int NT   = 512;          // threads per k_main block (8 waves)

// workspace layout (float offsets)
constexpr size_t OFF_KN   = 0;                                  // [T][B][D] normalized k
constexpr size_t OFF_E    = OFF_KN + (size_t)Tc * Bc * Dc;      // [T][B][D] sigmoid(erase)
constexpr size_t OFF_A    = OFF_E  + (size_t)Tc * Bc * Dc;      // [T][B][D] add
constexpr size_t OFF_RP   = OFF_A  + (size_t)Tc * Bc * Dc;      // [2][NW][B][D] f32 unnorm read partials
constexpr size_t OFF_DEN  = OFF_RP + (size_t)2 * NW * Bc * Dc;  // [T][B] den accumulators (atomicAdd)
constexpr size_t OFF_FLAGS= OFF_DEN + (size_t)Tc * Bc;          // 256*16 u32 arrival flags
}

DEV float sigm(float x) { return 1.0f / (1.0f + __expf(-x)); }

// Agent-scope relaxed helpers (proven coherent across XCDs, R3-R10).
DEV float ld1cg(const float* p) {
  unsigned u = __hip_atomic_load((const unsigned*)p, __ATOMIC_RELAXED,
                                 __HIP_MEMORY_SCOPE_AGENT);
  return __uint_as_float(u);
}
DEV void st1cg(float* p, float v) {
  __hip_atomic_store((unsigned*)p, __float_as_uint(v), __ATOMIC_RELAXED,
                     __HIP_MEMORY_SCOPE_AGENT);
}

// ---------------------------------------------------------------------------
// K1: 4 fused controller GEMMs (unchanged, validated).
// ---------------------------------------------------------------------------
__global__ __launch_bounds__(256) void k_gemm(
    const float* __restrict__ A,
    const float* __restrict__ Wk, const float* __restrict__ bk,
    const float* __restrict__ We, const float* __restrict__ be,
    const float* __restrict__ Ww, const float* __restrict__ bw,
    const float* __restrict__ Wg, const float* __restrict__ bg,
    float* __restrict__ ws, float* __restrict__ gout)
{
  __shared__ float As[32][68];
  __shared__ float Bs[32][68];

  const int bid = blockIdx.x;
  const int mat = bid >> 10;
  const int rem = bid & 1023;
  const int rt = rem >> 3, jt = rem & 7;
  const int rbase = rt * 64, jbase = jt * 64;

  const float* Wm; const float* bm;
  if      (mat == 0) { Wm = Wk; bm = bk; }
  else if (mat == 1) { Wm = We; bm = be; }
  else if (mat == 2) { Wm = Ww; bm = bw; }
  else               { Wm = Wg; bm = bg; }

  const int tid = threadIdx.x;
  const int lr = tid >> 2;
  const int lk = (tid & 3) * 8;
  const int ty = tid >> 4, tx = tid & 15;

  float acc[4][4] = {};

  for (int k0 = 0; k0 < Dc; k0 += 32) {
    const float4 a0 = *(const float4*)&A [(size_t)(rbase + lr) * Dc + k0 + lk];
    const float4 a1 = *(const float4*)&A [(size_t)(rbase + lr) * Dc + k0 + lk + 4];
    const float4 b0 = *(const float4*)&Wm[(size_t)(jbase + lr) * Dc + k0 + lk];
    const float4 b1 = *(const float4*)&Wm[(size_t)(jbase + lr) * Dc + k0 + lk + 4];
    __syncthreads();
    As[lk + 0][lr] = a0.x; As[lk + 1][lr] = a0.y; As[lk + 2][lr] = a0.z; As[lk + 3][lr] = a0.w;
    As[lk + 4][lr] = a1.x; As[lk + 5][lr] = a1.y; As[lk + 6][lr] = a1.z; As[lk + 7][lr] = a1.w;
    Bs[lk + 0][lr] = b0.x; Bs[lk + 1][lr] = b0.y; Bs[lk + 2][lr] = b0.z; Bs[lk + 3][lr] = b0.w;
    Bs[lk + 4][lr] = b1.x; Bs[lk + 5][lr] = b1.y; Bs[lk + 6][lr] = b1.z; Bs[lk + 7][lr] = b1.w;
    __syncthreads();
    #pragma unroll
    for (int kk = 0; kk < 32; ++kk) {
      const float4 av = *(const float4*)&As[kk][ty * 4];
      const float4 bv = *(const float4*)&Bs[kk][tx * 4];
      const float ar[4] = {av.x, av.y, av.z, av.w};
      const float br[4] = {bv.x, bv.y, bv.z, bv.w};
      #pragma unroll
      for (int i = 0; i < 4; ++i)
        #pragma unroll
        for (int j = 0; j < 4; ++j)
          acc[i][j] = fmaf(ar[i], br[j], acc[i][j]);
    }
  }

  const float4 bias = *(const float4*)&bm[jbase + tx * 4];
  const float bi[4] = {bias.x, bias.y, bias.z, bias.w};
  #pragma unroll
  for (int i = 0; i < 4; ++i) {
    const int r = rbase + ty * 4 + i;
    float v[4];
    #pragma unroll
    for (int j = 0; j < 4; ++j) {
      v[j] = acc[i][j] + bi[j];
      if (mat & 1) v[j] = sigm(v[j]);
    }
    float4 o; o.x = v[0]; o.y = v[1]; o.z = v[2]; o.w = v[3];
    if (mat == 3) {
      *(float4*)&gout[(size_t)r * Dc + jbase + tx * 4] = o;   // g -> d_out (temp)
    } else {
      float* dst = ws + (mat == 0 ? OFF_KN : (mat == 1 ? OFF_E : OFF_A));
      const int t = r & 255, b = r >> 8;                      // r = b*T + t
      *(float4*)&dst[((size_t)t * Bc + b) * Dc + jbase + tx * 4] = o;
    }
  }
}

// ---------------------------------------------------------------------------
// K2: l2-normalize k rows in place (unchanged).
// ---------------------------------------------------------------------------
__global__ __launch_bounds__(256) void k_knorm(float* __restrict__ kn)
{
  const int row = blockIdx.x * 4 + (threadIdx.x >> 6);
  const int lane = threadIdx.x & 63;
  float* p = kn + (size_t)row * Dc;
  float4 v0 = *(const float4*)&p[lane * 4];
  float4 v1 = *(const float4*)&p[256 + lane * 4];
  float ss = v0.x*v0.x + v0.y*v0.y + v0.z*v0.z + v0.w*v0.w
           + v1.x*v1.x + v1.y*v1.y + v1.z*v1.z + v1.w*v1.w;
  #pragma unroll
  for (int off = 32; off >= 1; off >>= 1) ss += __shfl_xor(ss, off);
  const float inv = 1.0f / fmaxf(sqrtf(ss), 1e-12f);
  v0.x *= inv; v0.y *= inv; v0.z *= inv; v0.w *= inv;
  v1.x *= inv; v1.y *= inv; v1.z *= inv; v1.w *= inv;
  *(float4*)&p[lane * 4] = v0;
  *(float4*)&p[256 + lane * 4] = v1;
}

// ---------------------------------------------------------------------------
// Single-hop all-to-all barrier; threads 0..255 poll one flag each (proven).
// ---------------------------------------------------------------------------
DEV void gbar(unsigned* flags, unsigned step, int bid, int tid)
{
  __syncthreads();                 // drains vmcnt per wave (stores + atomics)
  if (tid == 0)
    __hip_atomic_store(&flags[bid * 16], step, __ATOMIC_RELAXED,
                       __HIP_MEMORY_SCOPE_AGENT);
  if (tid < 256) {
    while (__hip_atomic_load(&flags[tid * 16], __ATOMIC_RELAXED,
                             __HIP_MEMORY_SCOPE_AGENT) < step)
      __builtin_amdgcn_s_sleep(1);
  }
  __syncthreads();
}

// ---------------------------------------------------------------------------
// sim phase (512t): thread = (row r = tid>>5, batch bp = tid&31).
// Ends with 32 atomicAdds into den[t+1] (device scope) instead of partials.
// ---------------------------------------------------------------------------
DEV void sim_phase(const float* __restrict__ knp, float* __restrict__ den_next,
                   const float (*y)[516], float* __restrict__ ew_own,
                   const float* invn_s, int tid)
{
  const int r = tid >> 5, bp = tid & 31;
  const float* kp = knp + (size_t)bp * Dc;
  float acc = 0.f;
  #pragma unroll 4
  for (int dq = 0; dq < Dc / 4; ++dq) {
    const float4 y4 = *(const float4*)&y[r][dq * 4];
    const float4 k4 = *(const float4*)&kp[dq * 4];
    acc = fmaf(y4.x, k4.x, acc); acc = fmaf(y4.y, k4.y, acc);
    acc = fmaf(y4.z, k4.z, acc); acc = fmaf(y4.w, k4.w, acc);
  }
  ew_own[tid] = __expf(acc * invn_s[r]);   // layout [r][bp] == tid
  __syncthreads();
  if (tid < 32) {
    float s = 0.f;
    #pragma unroll
    for (int r2 = 0; r2 < 16; ++r2) s += ew_own[r2 * 32 + tid];
    atomicAdd(&den_next[tid], s);          // device-scope accumulate
  }
}

// ---------------------------------------------------------------------------
// Persistent recurrent kernel: 256 blocks x 512 threads (2 waves/SIMD).
// rp is UNNORMALIZED (reducer applies 1/den); den read is one early load
// hidden under the rp pass.
// ---------------------------------------------------------------------------
__global__ __launch_bounds__(NT) void k_main(
    const float* __restrict__ cs, const float* __restrict__ mem_in,
    const float* __restrict__ gamma, const float* __restrict__ beta,
    float* __restrict__ ws, float* __restrict__ out)
{
  __shared__ float mrows[16][516];   // persistent memory rows (W)
  __shared__ float ew_own[512];      // [r][bp] exp(sim) at current t (W)
  __shared__ float wbuf[16][32];
  __shared__ float lds_red[512];     // reducer col reduce
  __shared__ float mu_s[16], rs_s[16], invn_s[16], dinv_s[32];

  float* kn   = ws + OFF_KN;
  float* eptb = ws + OFF_E;
  float* aptb = ws + OFF_A;
  float* rp   = ws + OFF_RP;
  float* den  = ws + OFF_DEN;
  unsigned* flags = (unsigned*)(ws + OFF_FLAGS);

  const int bid = blockIdx.x, tid = threadIdx.x;
  const float inv32 = 1.0f / 32.0f;
  const size_t RPPAR = (size_t)NW * Bc * Dc;

  float ev[32], av[32];                       // e[t]/a[t] resident (W)
  const float gmv = gamma[tid & 511];
  const float btv = beta[tid & 511];

  if (bid < NW) {
    const int s0 = bid * ROWS;
    #pragma unroll
    for (int r = 0; r < ROWS; ++r)
      mrows[r][tid] = mem_in[(size_t)(s0 + r) * Dc + tid];
    #pragma unroll
    for (int b = 0; b < 32; ++b) {
      ev[b] = eptb[(size_t)b * Dc + tid];
      av[b] = aptb[(size_t)b * Dc + tid];
    }
    __syncthreads();
    {
      const int row = tid >> 5, li = tid & 31;
      float ss = 0.f;
      #pragma unroll
      for (int i = 0; i < 4; ++i) {
        const float4 v = *(const float4*)&mrows[row][(li + i * 32) * 4];
        ss += v.x*v.x + v.y*v.y + v.z*v.z + v.w*v.w;
      }
      ss += __shfl_xor(ss, 16); ss += __shfl_xor(ss, 8);
      ss += __shfl_xor(ss, 4);  ss += __shfl_xor(ss, 2);
      ss += __shfl_xor(ss, 1);
      if (li == 0) invn_s[row] = 1.0f / fmaxf(sqrtf(ss), 1e-12f);
    }
    __syncthreads();
    sim_phase(kn, den, mrows, ew_own, invn_s, tid);   // accumulates den[0]
  }
  gbar(flags, 1u, bid, tid);

  for (int t = 0; t <= Tc; ++t) {
    if (bid < NW) {
      if (t < Tc) {
        // 0) issue den[t] load early; consumed after the rp pass
        float dv = 0.f;
        if (tid < 32) dv = ld1cg(&den[(size_t)t * Bc + tid]);

        // 1) UNNORMALIZED rp pass straight from ew_own (no den dependency)
        float mr[16];
        #pragma unroll
        for (int r = 0; r < ROWS; ++r) mr[r] = mrows[r][tid];
        {
          float rpv[32] = {};
          #pragma unroll
          for (int r = 0; r < ROWS; ++r) {
            const float mrr = mr[r];
            #pragma unroll
            for (int b4 = 0; b4 < 8; ++b4) {
              const float4 e4 = *(const float4*)&ew_own[r * 32 + b4 * 4];
              rpv[b4*4+0] = fmaf(e4.x, mrr, rpv[b4*4+0]);
              rpv[b4*4+1] = fmaf(e4.y, mrr, rpv[b4*4+1]);
              rpv[b4*4+2] = fmaf(e4.z, mrr, rpv[b4*4+2]);
              rpv[b4*4+3] = fmaf(e4.w, mrr, rpv[b4*4+3]);
            }
          }
          float* rpd = rp + (size_t)(t & 1) * RPPAR
                     + (size_t)bid * Bc * Dc + tid;
          #pragma unroll
          for (int b = 0; b < 32; ++b) st1cg(&rpd[(size_t)b * Dc], rpv[b]);
        }

        if (t < Tc - 1) {
          // 2) den arrived by now; build normalized weights
          if (tid < 32) dinv_s[tid] = 1.0f / dv;
          __syncthreads();
          wbuf[tid >> 5][tid & 31] = ew_own[tid] * dinv_s[tid & 31];
          __syncthreads();

          // 3) erase/add pass (R10-proven)
          float er[16] = {}, ad[16] = {};
          #pragma unroll
          for (int r = 0; r < ROWS; ++r) {
            #pragma unroll
            for (int b4 = 0; b4 < 8; ++b4) {
              const float4 w4 = *(const float4*)&wbuf[r][b4 * 4];
              er[r] = fmaf(w4.x, ev[b4*4+0], er[r]);
              er[r] = fmaf(w4.y, ev[b4*4+1], er[r]);
              er[r] = fmaf(w4.z, ev[b4*4+2], er[r]);
              er[r] = fmaf(w4.w, ev[b4*4+3], er[r]);
              ad[r] = fmaf(w4.x, av[b4*4+0], ad[r]);
              ad[r] = fmaf(w4.y, av[b4*4+1], ad[r]);
              ad[r] = fmaf(w4.z, av[b4*4+2], ad[r]);
              ad[r] = fmaf(w4.w, av[b4*4+3], ad[r]);
            }
          }
          // 4) x = m*(1-er/32) + ad/32, staged to mrows
          float xr[16];
          #pragma unroll
          for (int r = 0; r < ROWS; ++r) {
            const float x = mr[r] * (1.0f - er[r] * inv32) + ad[r] * inv32;
            xr[r] = x;
            mrows[r][tid] = x;
          }
          // 5) prefetch e/a for t+1
          if (t <= Tc - 3) {
            const float* ep1 = eptb + (size_t)(t + 1) * Bc * Dc;
            const float* ap1 = aptb + (size_t)(t + 1) * Bc * Dc;
            #pragma unroll
            for (int b = 0; b < 32; ++b) {
              ev[b] = ep1[(size_t)b * Dc + tid];
              av[b] = ap1[(size_t)b * Dc + tid];
            }
          }
          __syncthreads();
          // 6) LN stats
          {
            const int row = tid >> 5, li = tid & 31;
            float s1 = 0.f, s2 = 0.f;
            #pragma unroll
            for (int i = 0; i < 4; ++i) {
              const float4 v = *(const float4*)&mrows[row][(li + i * 32) * 4];
              s1 += v.x + v.y + v.z + v.w;
              s2 += v.x*v.x + v.y*v.y + v.z*v.z + v.w*v.w;
            }
            s1 += __shfl_xor(s1, 16); s2 += __shfl_xor(s2, 16);
            s1 += __shfl_xor(s1, 8);  s2 += __shfl_xor(s2, 8);
            s1 += __shfl_xor(s1, 4);  s2 += __shfl_xor(s2, 4);
            s1 += __shfl_xor(s1, 2);  s2 += __shfl_xor(s2, 2);
            s1 += __shfl_xor(s1, 1);  s2 += __shfl_xor(s2, 1);
            if (li == 0) {
              const float mu = s1 * (1.0f / 512.0f);
              const float var = s2 * (1.0f / 512.0f) - mu * mu;
              mu_s[row] = mu;
              rs_s[row] = rsqrtf(var + 1e-5f);
            }
          }
          __syncthreads();
          // 7) apply LN into mrows
          #pragma unroll
          for (int r = 0; r < ROWS; ++r) {
            const float y = (xr[r] - mu_s[r]) * rs_s[r] * gmv + btv;
            mrows[r][tid] = y;
          }
          __syncthreads();
          // 8) row l2 norms
          {
            const int row = tid >> 5, li = tid & 31;
            float ss = 0.f;
            #pragma unroll
            for (int i = 0; i < 4; ++i) {
              const float4 v = *(const float4*)&mrows[row][(li + i * 32) * 4];
              ss += v.x*v.x + v.y*v.y + v.z*v.z + v.w*v.w;
            }
            ss += __shfl_xor(ss, 16); ss += __shfl_xor(ss, 8);
            ss += __shfl_xor(ss, 4);  ss += __shfl_xor(ss, 2);
            ss += __shfl_xor(ss, 1);
            if (li == 0) invn_s[row] = 1.0f / fmaxf(sqrtf(ss), 1e-12f);
          }
          __syncthreads();
          // 9) sim for t+1 -> atomicAdd den[t+1]
          sim_phase(kn + (size_t)(t + 1) * Bc * Dc,
                    den + (size_t)(t + 1) * Bc,
                    mrows, ew_own, invn_s, tid);
        }
      }
    } else {
      // Reducer: out for step t-1; applies 1/den[t0][b] to the summed rp.
      if (t >= 1) {
        const int t0 = t - 1;
        const int rb = bid - NW;
        const int b = rb >> 2;
        const int d0 = (rb & 3) * 128;
        const float dvb = ld1cg(&den[(size_t)t0 * Bc + b]);   // uniform
        const float* rpp = rp + (size_t)(t0 & 1) * RPPAR;
        const int pg = tid >> 7;          // 0..3
        const int c  = tid & 127;
        float acc = 0.f;
        #pragma unroll 4
        for (int i = 0; i < 32; ++i) {
          const int p = pg * 32 + i;
          acc += ld1cg(&rpp[((size_t)p * Bc + b) * Dc + d0 + c]);
        }
        lds_red[pg * 128 + c] = acc;
        __syncthreads();
        if (tid < 128) {
          const float s = (lds_red[tid] + lds_red[128 + tid]
                        + lds_red[256 + tid] + lds_red[384 + tid]) / dvb;
          const size_t oofs = ((size_t)b * Tc + t0) * Dc + d0 + tid;
          const float g  = out[oofs];
          const float cv = cs[oofs];
          out[oofs] = g * cv + (1.0f - g) * s;
        }
        __syncthreads();
      }
    }
    if (t < Tc) gbar(flags, (unsigned)(t + 2), bid, tid);
  }
}

// ---------------------------------------------------------------------------
extern "C" void kernel_launch(void* const* d_in, const int* in_sizes, int n_in,
                              void* d_out, int out_size, void* d_ws, size_t ws_size,
                              hipStream_t stream)
{
  const float* cs    = (const float*)d_in[0];
  const float* mem   = (const float*)d_in[1];
  const float* Wk    = (const float*)d_in[2];
  const float* bk    = (const float*)d_in[3];
  const float* We    = (const float*)d_in[4];
  const float* be    = (const float*)d_in[5];
  const float* Ww    = (const float*)d_in[6];
  const float* bw    = (const float*)d_in[7];
  const float* Wg    = (const float*)d_in[8];
  const float* bg    = (const float*)d_in[9];
  const float* gamma = (const float*)d_in[10];
  const float* beta  = (const float*)d_in[11];
  float* ws  = (float*)d_ws;
  float* out = (float*)d_out;

  // zero den accumulators + barrier flags (contiguous region)
  hipMemsetAsync(ws + OFF_DEN, 0,
                 ((size_t)Tc * Bc + 256 * 16) * sizeof(float), stream);

  hipLaunchKernelGGL(k_gemm, dim3(4096), dim3(256), 0, stream,
                     cs, Wk, bk, We, be, Ww, bw, Wg, bg, ws, out);
  hipLaunchKernelGGL(k_knorm, dim3(2048), dim3(256), 0, stream, ws + OFF_KN);
  hipLaunchKernelGGL(k_main, dim3(NBLK), dim3(NT), 0, stream,
                     cs, mem, gamma, beta, ws, out);
}

// Round 13
// 10137.940 us; speedup vs baseline: 3.7237x; 1.1384x over previous
//
#include <hip/hip_runtime.h>

#define DEV __device__ __forceinline__

namespace {
constexpr int Bc = 32;
constexpr int Tc = 256;
constexpr int Dc = 512;
constexpr int NBLK = 256;
constexpr int NW   = 128;          // writer blocks (own 16 mem rows each)
constexpr int ROWS = 16;
constexpr int NT   = 512;          // threads per k_main block (8 waves)
constexpr int FTOT = Bc * Dc;      // 16384 floats per rp partial

constexpr size_t RPPAR = (size_t)NW * FTOT;   // rp floats per parity
constexpr size_t XSPAR = (size_t)8 * FTOT;    // xsum floats per parity

// workspace layout (float offsets)
constexpr size_t OFF_KN   = 0;                                  // [T][B][D] normalized k
constexpr size_t OFF_E    = OFF_KN + (size_t)Tc * Bc * Dc;      // [T][B][D] sigmoid(erase)
constexpr size_t OFF_A    = OFF_E  + (size_t)Tc * Bc * Dc;      // [T][B][D] add
constexpr size_t OFF_RP   = OFF_A  + (size_t)Tc * Bc * Dc;      // [2][NW][B][D] unnorm read partials
constexpr size_t OFF_XS   = OFF_RP + 2 * RPPAR;                 // [2][8][B][D] per-XCD sums
constexpr size_t OFF_DEN  = OFF_XS + 2 * XSPAR;                 // [T][B] den accumulators
constexpr size_t OFF_MAP  = OFF_DEN + (size_t)Tc * Bc;          // [256] block->XCD map
constexpr size_t OFF_FLAGS= OFF_MAP + 256;                      // 256*16 u32 arrival flags
}

DEV float sigm(float x) { return 1.0f / (1.0f + __expf(-x)); }

// Agent-scope relaxed helpers (proven coherent across XCDs, R3-R12).
DEV float ld1cg(const float* p) {
  unsigned u = __hip_atomic_load((const unsigned*)p, __ATOMIC_RELAXED,
                                 __HIP_MEMORY_SCOPE_AGENT);
  return __uint_as_float(u);
}
DEV void st1cg(float* p, float v) {
  __hip_atomic_store((unsigned*)p, __float_as_uint(v), __ATOMIC_RELAXED,
                     __HIP_MEMORY_SCOPE_AGENT);
}
DEV unsigned ldu32cg(const unsigned* p) {
  return __hip_atomic_load(p, __ATOMIC_RELAXED, __HIP_MEMORY_SCOPE_AGENT);
}
DEV void stu32cg(unsigned* p, unsigned v) {
  __hip_atomic_store(p, v, __ATOMIC_RELAXED, __HIP_MEMORY_SCOPE_AGENT);
}

// sc0-only loads: bypass L1, hit the (XCD-local) L2 where same-XCD plain
// stores are coherent. Batched 8 with one trailing vmcnt.
DEV float red8_sc0(const float* p0, const float* p1, const float* p2,
                   const float* p3, const float* p4, const float* p5,
                   const float* p6, const float* p7) {
  float r0, r1, r2, r3, r4, r5, r6, r7;
  asm volatile(
    "global_load_dword %0, %8, off sc0\n\t"
    "global_load_dword %1, %9, off sc0\n\t"
    "global_load_dword %2, %10, off sc0\n\t"
    "global_load_dword %3, %11, off sc0\n\t"
    "global_load_dword %4, %12, off sc0\n\t"
    "global_load_dword %5, %13, off sc0\n\t"
    "global_load_dword %6, %14, off sc0\n\t"
    "global_load_dword %7, %15, off sc0\n\t"
    "s_waitcnt vmcnt(0)"
    : "=&v"(r0), "=&v"(r1), "=&v"(r2), "=&v"(r3),
      "=&v"(r4), "=&v"(r5), "=&v"(r6), "=&v"(r7)
    : "v"(p0), "v"(p1), "v"(p2), "v"(p3), "v"(p4), "v"(p5), "v"(p6), "v"(p7)
    : "memory");
  return ((r0 + r1) + (r2 + r3)) + ((r4 + r5) + (r6 + r7));
}

DEV float red16_xcd(const float* rpb, const int* wls, int f) {
  const float* q0  = rpb + (size_t)wls[0]  * FTOT + f;
  const float* q1  = rpb + (size_t)wls[1]  * FTOT + f;
  const float* q2  = rpb + (size_t)wls[2]  * FTOT + f;
  const float* q3  = rpb + (size_t)wls[3]  * FTOT + f;
  const float* q4  = rpb + (size_t)wls[4]  * FTOT + f;
  const float* q5  = rpb + (size_t)wls[5]  * FTOT + f;
  const float* q6  = rpb + (size_t)wls[6]  * FTOT + f;
  const float* q7  = rpb + (size_t)wls[7]  * FTOT + f;
  const float* q8  = rpb + (size_t)wls[8]  * FTOT + f;
  const float* q9  = rpb + (size_t)wls[9]  * FTOT + f;
  const float* q10 = rpb + (size_t)wls[10] * FTOT + f;
  const float* q11 = rpb + (size_t)wls[11] * FTOT + f;
  const float* q12 = rpb + (size_t)wls[12] * FTOT + f;
  const float* q13 = rpb + (size_t)wls[13] * FTOT + f;
  const float* q14 = rpb + (size_t)wls[14] * FTOT + f;
  const float* q15 = rpb + (size_t)wls[15] * FTOT + f;
  const float s0 = red8_sc0(q0, q1, q2, q3, q4, q5, q6, q7);
  const float s1 = red8_sc0(q8, q9, q10, q11, q12, q13, q14, q15);
  return s0 + s1;
}

// ---------------------------------------------------------------------------
// K1: 4 fused controller GEMMs (unchanged, validated).
// ---------------------------------------------------------------------------
__global__ __launch_bounds__(256) void k_gemm(
    const float* __restrict__ A,
    const float* __restrict__ Wk, const float* __restrict__ bk,
    const float* __restrict__ We, const float* __restrict__ be,
    const float* __restrict__ Ww, const float* __restrict__ bw,
    const float* __restrict__ Wg, const float* __restrict__ bg,
    float* __restrict__ ws, float* __restrict__ gout)
{
  __shared__ float As[32][68];
  __shared__ float Bs[32][68];

  const int bid = blockIdx.x;
  const int mat = bid >> 10;
  const int rem = bid & 1023;
  const int rt = rem >> 3, jt = rem & 7;
  const int rbase = rt * 64, jbase = jt * 64;

  const float* Wm; const float* bm;
  if      (mat == 0) { Wm = Wk; bm = bk; }
  else if (mat == 1) { Wm = We; bm = be; }
  else if (mat == 2) { Wm = Ww; bm = bw; }
  else               { Wm = Wg; bm = bg; }

  const int tid = threadIdx.x;
  const int lr = tid >> 2;
  const int lk = (tid & 3) * 8;
  const int ty = tid >> 4, tx = tid & 15;

  float acc[4][4] = {};

  for (int k0 = 0; k0 < Dc; k0 += 32) {
    const float4 a0 = *(const float4*)&A [(size_t)(rbase + lr) * Dc + k0 + lk];
    const float4 a1 = *(const float4*)&A [(size_t)(rbase + lr) * Dc + k0 + lk + 4];
    const float4 b0 = *(const float4*)&Wm[(size_t)(jbase + lr) * Dc + k0 + lk];
    const float4 b1 = *(const float4*)&Wm[(size_t)(jbase + lr) * Dc + k0 + lk + 4];
    __syncthreads();
    As[lk + 0][lr] = a0.x; As[lk + 1][lr] = a0.y; As[lk + 2][lr] = a0.z; As[lk + 3][lr] = a0.w;
    As[lk + 4][lr] = a1.x; As[lk + 5][lr] = a1.y; As[lk + 6][lr] = a1.z; As[lk + 7][lr] = a1.w;
    Bs[lk + 0][lr] = b0.x; Bs[lk + 1][lr] = b0.y; Bs[lk + 2][lr] = b0.z; Bs[lk + 3][lr] = b0.w;
    Bs[lk + 4][lr] = b1.x; Bs[lk + 5][lr] = b1.y; Bs[lk + 6][lr] = b1.z; Bs[lk + 7][lr] = b1.w;
    __syncthreads();
    #pragma unroll
    for (int kk = 0; kk < 32; ++kk) {
      const float4 av = *(const float4*)&As[kk][ty * 4];
      const float4 bv = *(const float4*)&Bs[kk][tx * 4];
      const float ar[4] = {av.x, av.y, av.z, av.w};
      const float br[4] = {bv.x, bv.y, bv.z, bv.w};
      #pragma unroll
      for (int i = 0; i < 4; ++i)
        #pragma unroll
        for (int j = 0; j < 4; ++j)
          acc[i][j] = fmaf(ar[i], br[j], acc[i][j]);
    }
  }

  const float4 bias = *(const float4*)&bm[jbase + tx * 4];
  const float bi[4] = {bias.x, bias.y, bias.z, bias.w};
  #pragma unroll
  for (int i = 0; i < 4; ++i) {
    const int r = rbase + ty * 4 + i;
    float v[4];
    #pragma unroll
    for (int j = 0; j < 4; ++j) {
      v[j] = acc[i][j] + bi[j];
      if (mat & 1) v[j] = sigm(v[j]);
    }
    float4 o; o.x = v[0]; o.y = v[1]; o.z = v[2]; o.w = v[3];
    if (mat == 3) {
      *(float4*)&gout[(size_t)r * Dc + jbase + tx * 4] = o;   // g -> d_out (temp)
    } else {
      float* dst = ws + (mat == 0 ? OFF_KN : (mat == 1 ? OFF_E : OFF_A));
      const int t = r & 255, b = r >> 8;                      // r = b*T + t
      *(float4*)&dst[((size_t)t * Bc + b) * Dc + jbase + tx * 4] = o;
    }
  }
}

// ---------------------------------------------------------------------------
// K2: l2-normalize k rows in place (unchanged).
// ---------------------------------------------------------------------------
__global__ __launch_bounds__(256) void k_knorm(float* __restrict__ kn)
{
  const int row = blockIdx.x * 4 + (threadIdx.x >> 6);
  const int lane = threadIdx.x & 63;
  float* p = kn + (size_t)row * Dc;
  float4 v0 = *(const float4*)&p[lane * 4];
  float4 v1 = *(const float4*)&p[256 + lane * 4];
  float ss = v0.x*v0.x + v0.y*v0.y + v0.z*v0.z + v0.w*v0.w
           + v1.x*v1.x + v1.y*v1.y + v1.z*v1.z + v1.w*v1.w;
  #pragma unroll
  for (int off = 32; off >= 1; off >>= 1) ss += __shfl_xor(ss, off);
  const float inv = 1.0f / fmaxf(sqrtf(ss), 1e-12f);
  v0.x *= inv; v0.y *= inv; v0.z *= inv; v0.w *= inv;
  v1.x *= inv; v1.y *= inv; v1.z *= inv; v1.w *= inv;
  *(float4*)&p[lane * 4] = v0;
  *(float4*)&p[256 + lane * 4] = v1;
}

// ---------------------------------------------------------------------------
// Single-hop all-to-all barrier; threads 0..255 poll one flag each (proven).
// ---------------------------------------------------------------------------
DEV void gbar(unsigned* flags, unsigned step, int bid, int tid)
{
  __syncthreads();                 // drains vmcnt per wave (plain + sc1 + asm)
  if (tid == 0)
    __hip_atomic_store(&flags[bid * 16], step, __ATOMIC_RELAXED,
                       __HIP_MEMORY_SCOPE_AGENT);
  if (tid < 256) {
    while (__hip_atomic_load(&flags[tid * 16], __ATOMIC_RELAXED,
                             __HIP_MEMORY_SCOPE_AGENT) < step)
      __builtin_amdgcn_s_sleep(1);
  }
  __syncthreads();
}

// ---------------------------------------------------------------------------
// sim phase (512t): thread = (row r = tid>>5, batch bp = tid&31).
// Ends with 32 device-scope atomicAdds into den[t+1] (R12-proven).
// ---------------------------------------------------------------------------
DEV void sim_phase(const float* __restrict__ knp, float* __restrict__ den_next,
                   const float (*y)[516], float* __restrict__ ew_own,
                   const float* invn_s, int tid)
{
  const int r = tid >> 5, bp = tid & 31;
  const float* kp = knp + (size_t)bp * Dc;
  float acc = 0.f;
  #pragma unroll 4
  for (int dq = 0; dq < Dc / 4; ++dq) {
    const float4 y4 = *(const float4*)&y[r][dq * 4];
    const float4 k4 = *(const float4*)&kp[dq * 4];
    acc = fmaf(y4.x, k4.x, acc); acc = fmaf(y4.y, k4.y, acc);
    acc = fmaf(y4.z, k4.z, acc); acc = fmaf(y4.w, k4.w, acc);
  }
  ew_own[tid] = __expf(acc * invn_s[r]);   // layout [r][bp] == tid
  __syncthreads();
  if (tid < 32) {
    float s = 0.f;
    #pragma unroll
    for (int r2 = 0; r2 < 16; ++r2) s += ew_own[r2 * 32 + tid];
    atomicAdd(&den_next[tid], s);          // device-scope accumulate
  }
}

// ---------------------------------------------------------------------------
// Persistent recurrent kernel: 256 blocks x 512 threads (2 waves/SIMD).
// Fast path (when block->XCD map is 16W+16R per XCD): rp via plain stores
// into local L2; per-XCD stage-A reduction with sc0 loads; only the 8 XCD
// sums (512 KB/step) cross XCDs via sc1. Fallback = R12 path (proven).
// ---------------------------------------------------------------------------
__global__ __launch_bounds__(NT) void k_main(
    const float* __restrict__ cs, const float* __restrict__ mem_in,
    const float* __restrict__ gamma, const float* __restrict__ beta,
    float* __restrict__ ws, float* __restrict__ out)
{
  __shared__ float mrows[16][516];   // persistent memory rows (W)
  __shared__ float ew_own[512];      // [r][bp] exp(sim) at current t (W)
  __shared__ float wbuf[16][32];
  __shared__ float lds_red[512];     // fallback reducer col reduce
  __shared__ float mu_s[16], rs_s[16], invn_s[16], dinv_s[32];
  __shared__ int   xmap_s[256];
  __shared__ int   wls[16];
  __shared__ int   cwx[8], crx[8];
  __shared__ int   sFast, sRank;

  float* kn   = ws + OFF_KN;
  float* eptb = ws + OFF_E;
  float* aptb = ws + OFF_A;
  float* rp   = ws + OFF_RP;
  float* xs   = ws + OFF_XS;
  float* den  = ws + OFF_DEN;
  unsigned* map_  = (unsigned*)(ws + OFF_MAP);
  unsigned* flags = (unsigned*)(ws + OFF_FLAGS);

  const int bid = blockIdx.x, tid = threadIdx.x;
  const float inv32 = 1.0f / 32.0f;

  // physical XCD id (HW_REG_XCC_ID = 20, 4 bits) — partition key for L2 pairing
  const int myxcd = __builtin_amdgcn_s_getreg((3 << 11) | 20) & 7;
  if (tid == 0) stu32cg(&map_[bid], (unsigned)myxcd);

  float ev[32], av[32];                       // e[t]/a[t] resident (W)
  const float gmv = gamma[tid & 511];
  const float btv = beta[tid & 511];

  if (bid < NW) {
    const int s0 = bid * ROWS;
    #pragma unroll
    for (int r = 0; r < ROWS; ++r)
      mrows[r][tid] = mem_in[(size_t)(s0 + r) * Dc + tid];
    #pragma unroll
    for (int b = 0; b < 32; ++b) {
      ev[b] = eptb[(size_t)b * Dc + tid];
      av[b] = aptb[(size_t)b * Dc + tid];
    }
    __syncthreads();
    {
      const int row = tid >> 5, li = tid & 31;
      float ss = 0.f;
      #pragma unroll
      for (int i = 0; i < 4; ++i) {
        const float4 v = *(const float4*)&mrows[row][(li + i * 32) * 4];
        ss += v.x*v.x + v.y*v.y + v.z*v.z + v.w*v.w;
      }
      ss += __shfl_xor(ss, 16); ss += __shfl_xor(ss, 8);
      ss += __shfl_xor(ss, 4);  ss += __shfl_xor(ss, 2);
      ss += __shfl_xor(ss, 1);
      if (li == 0) invn_s[row] = 1.0f / fmaxf(sqrtf(ss), 1e-12f);
    }
    __syncthreads();
    sim_phase(kn, den, mrows, ew_own, invn_s, tid);   // accumulates den[0]
  }
  gbar(flags, 1u, bid, tid);

  // ----- map analysis: decide fast/fallback deterministically -----
  if (tid < 256) xmap_s[tid] = (int)(ldu32cg(&map_[tid]) & 7u);
  if (tid < 8) { cwx[tid] = 0; crx[tid] = 0; }
  __syncthreads();
  if (tid == 0) {
    int nl = 0, rk = 0;
    for (int i = 0; i < NW; ++i) {
      const int x = xmap_s[i];
      cwx[x]++;
      if (bid >= NW && x == myxcd && nl < 16) wls[nl++] = i;
    }
    for (int i = NW; i < NBLK; ++i) {
      const int x = xmap_s[i];
      if (i == bid) rk = crx[x];
      crx[x]++;
    }
    int ok = 1;
    for (int j = 0; j < 8; ++j) ok &= (cwx[j] == 16) & (crx[j] == 16);
    sFast = ok; sRank = rk;
  }
  __syncthreads();
  const int fastP = sFast;
  const int rkBase = sRank * 1024;

  for (int t = 0; t <= Tc + 1; ++t) {
    if (bid < NW) {
      if (t < Tc) {
        // 0) issue den[t] load early; consumed after the rp pass
        float dv = 0.f;
        if (tid < 32) dv = ld1cg(&den[(size_t)t * Bc + tid]);

        // 1) UNNORMALIZED rp pass straight from ew_own
        float mr[16];
        #pragma unroll
        for (int r = 0; r < ROWS; ++r) mr[r] = mrows[r][tid];
        {
          float rpv[32] = {};
          #pragma unroll
          for (int r = 0; r < ROWS; ++r) {
            const float mrr = mr[r];
            #pragma unroll
            for (int b4 = 0; b4 < 8; ++b4) {
              const float4 e4 = *(const float4*)&ew_own[r * 32 + b4 * 4];
              rpv[b4*4+0] = fmaf(e4.x, mrr, rpv[b4*4+0]);
              rpv[b4*4+1] = fmaf(e4.y, mrr, rpv[b4*4+1]);
              rpv[b4*4+2] = fmaf(e4.z, mrr, rpv[b4*4+2]);
              rpv[b4*4+3] = fmaf(e4.w, mrr, rpv[b4*4+3]);
            }
          }
          float* rpd = rp + (size_t)(t & 1) * RPPAR + (size_t)bid * FTOT + tid;
          if (fastP) {
            // plain stores -> local L2 (read by same-XCD stage-A reducers)
            #pragma unroll
            for (int b = 0; b < 32; ++b) rpd[(size_t)b * Dc] = rpv[b];
          } else {
            #pragma unroll
            for (int b = 0; b < 32; ++b) st1cg(&rpd[(size_t)b * Dc], rpv[b]);
          }
        }

        if (t < Tc - 1) {
          // 2) den arrived; normalized weights
          if (tid < 32) dinv_s[tid] = 1.0f / dv;
          __syncthreads();
          wbuf[tid >> 5][tid & 31] = ew_own[tid] * dinv_s[tid & 31];
          __syncthreads();

          // 3) erase/add pass
          float er[16] = {}, ad[16] = {};
          #pragma unroll
          for (int r = 0; r < ROWS; ++r) {
            #pragma unroll
            for (int b4 = 0; b4 < 8; ++b4) {
              const float4 w4 = *(const float4*)&wbuf[r][b4 * 4];
              er[r] = fmaf(w4.x, ev[b4*4+0], er[r]);
              er[r] = fmaf(w4.y, ev[b4*4+1], er[r]);
              er[r] = fmaf(w4.z, ev[b4*4+2], er[r]);
              er[r] = fmaf(w4.w, ev[b4*4+3], er[r]);
              ad[r] = fmaf(w4.x, av[b4*4+0], ad[r]);
              ad[r] = fmaf(w4.y, av[b4*4+1], ad[r]);
              ad[r] = fmaf(w4.z, av[b4*4+2], ad[r]);
              ad[r] = fmaf(w4.w, av[b4*4+3], ad[r]);
            }
          }
          // 4) x = m*(1-er/32) + ad/32
          float xr[16];
          #pragma unroll
          for (int r = 0; r < ROWS; ++r) {
            const float x = mr[r] * (1.0f - er[r] * inv32) + ad[r] * inv32;
            xr[r] = x;
            mrows[r][tid] = x;
          }
          // 5) prefetch e/a for t+1
          if (t <= Tc - 3) {
            const float* ep1 = eptb + (size_t)(t + 1) * Bc * Dc;
            const float* ap1 = aptb + (size_t)(t + 1) * Bc * Dc;
            #pragma unroll
            for (int b = 0; b < 32; ++b) {
              ev[b] = ep1[(size_t)b * Dc + tid];
              av[b] = ap1[(size_t)b * Dc + tid];
            }
          }
          __syncthreads();
          // 6) LN stats
          {
            const int row = tid >> 5, li = tid & 31;
            float s1 = 0.f, s2 = 0.f;
            #pragma unroll
            for (int i = 0; i < 4; ++i) {
              const float4 v = *(const float4*)&mrows[row][(li + i * 32) * 4];
              s1 += v.x + v.y + v.z + v.w;
              s2 += v.x*v.x + v.y*v.y + v.z*v.z + v.w*v.w;
            }
            s1 += __shfl_xor(s1, 16); s2 += __shfl_xor(s2, 16);
            s1 += __shfl_xor(s1, 8);  s2 += __shfl_xor(s2, 8);
            s1 += __shfl_xor(s1, 4);  s2 += __shfl_xor(s2, 4);
            s1 += __shfl_xor(s1, 2);  s2 += __shfl_xor(s2, 2);
            s1 += __shfl_xor(s1, 1);  s2 += __shfl_xor(s2, 1);
            if (li == 0) {
              const float mu = s1 * (1.0f / 512.0f);
              const float var = s2 * (1.0f / 512.0f) - mu * mu;
              mu_s[row] = mu;
              rs_s[row] = rsqrtf(var + 1e-5f);
            }
          }
          __syncthreads();
          // 7) apply LN
          #pragma unroll
          for (int r = 0; r < ROWS; ++r) {
            const float y = (xr[r] - mu_s[r]) * rs_s[r] * gmv + btv;
            mrows[r][tid] = y;
          }
          __syncthreads();
          // 8) row l2 norms
          {
            const int row = tid >> 5, li = tid & 31;
            float ss = 0.f;
            #pragma unroll
            for (int i = 0; i < 4; ++i) {
              const float4 v = *(const float4*)&mrows[row][(li + i * 32) * 4];
              ss += v.x*v.x + v.y*v.y + v.z*v.z + v.w*v.w;
            }
            ss += __shfl_xor(ss, 16); ss += __shfl_xor(ss, 8);
            ss += __shfl_xor(ss, 4);  ss += __shfl_xor(ss, 2);
            ss += __shfl_xor(ss, 1);
            if (li == 0) invn_s[row] = 1.0f / fmaxf(sqrtf(ss), 1e-12f);
          }
          __syncthreads();
          // 9) sim for t+1 -> atomicAdd den[t+1]
          sim_phase(kn + (size_t)(t + 1) * Bc * Dc,
                    den + (size_t)(t + 1) * Bc,
                    mrows, ew_own, invn_s, tid);
        }
      }
    } else if (fastP) {
      // ---- fast path: two-stage reduction ----
      // Stage A (t0 = t-1): sum my XCD's 16 partials from local L2 (sc0).
      if (t >= 1 && t <= Tc) {
        const int pa = (t - 1) & 1;
        const float* rpb = rp + (size_t)pa * RPPAR;
        float* xsb = xs + (size_t)pa * XSPAR + (size_t)myxcd * FTOT;
        {
          const int f = rkBase + tid;
          st1cg(&xsb[f], red16_xcd(rpb, wls, f));
        }
        {
          const int f = rkBase + 512 + tid;
          st1cg(&xsb[f], red16_xcd(rpb, wls, f));
        }
      }
      // Stage B (t0 = t-2): sum the 8 XCD sums (sc1), normalize, gated out.
      if (t >= 2) {
        const int t0 = t - 2;
        const int pb = t0 & 1;
        if (tid < 128) {
          const int rb = bid - NW;
          const int b = rb >> 2;
          const int d0 = (rb & 3) * 128;
          const float dvb = ld1cg(&den[(size_t)t0 * Bc + b]);
          const float* xsb = xs + (size_t)pb * XSPAR;
          const size_t o = (size_t)b * Dc + d0 + tid;
          float s = 0.f;
          #pragma unroll
          for (int j = 0; j < 8; ++j) s += ld1cg(&xsb[(size_t)j * FTOT + o]);
          const size_t oofs = ((size_t)b * Tc + t0) * Dc + d0 + tid;
          const float g  = out[oofs];
          const float cv = cs[oofs];
          out[oofs] = g * cv + (1.0f - g) * (s / dvb);
        }
        __syncthreads();
      }
    } else {
      // ---- fallback: R12 single-stage sc1 reduction (proven) ----
      if (t >= 1 && t <= Tc) {
        const int t0 = t - 1;
        const int rb = bid - NW;
        const int b = rb >> 2;
        const int d0 = (rb & 3) * 128;
        const float dvb = ld1cg(&den[(size_t)t0 * Bc + b]);
        const float* rpp = rp + (size_t)(t0 & 1) * RPPAR;
        const int pg = tid >> 7;
        const int c  = tid & 127;
        float acc = 0.f;
        #pragma unroll 4
        for (int i = 0; i < 32; ++i) {
          const int p = pg * 32 + i;
          acc += ld1cg(&rpp[((size_t)p * Bc + b) * Dc + d0 + c]);
        }
        lds_red[pg * 128 + c] = acc;
        __syncthreads();
        if (tid < 128) {
          const float s = (lds_red[tid] + lds_red[128 + tid]
                        + lds_red[256 + tid] + lds_red[384 + tid]) / dvb;
          const size_t oofs = ((size_t)b * Tc + t0) * Dc + d0 + tid;
          const float g  = out[oofs];
          const float cv = cs[oofs];
          out[oofs] = g * cv + (1.0f - g) * s;
        }
        __syncthreads();
      }
    }
    if (t < Tc + 1) gbar(flags, (unsigned)(t + 2), bid, tid);
  }
}

// ---------------------------------------------------------------------------
extern "C" void kernel_launch(void* const* d_in, const int* in_sizes, int n_in,
                              void* d_out, int out_size, void* d_ws, size_t ws_size,
                              hipStream_t stream)
{
  const float* cs    = (const float*)d_in[0];
  const float* mem   = (const float*)d_in[1];
  const float* Wk    = (const float*)d_in[2];
  const float* bk    = (const float*)d_in[3];
  const float* We    = (const float*)d_in[4];
  const float* be    = (const float*)d_in[5];
  const float* Ww    = (const float*)d_in[6];
  const float* bw    = (const float*)d_in[7];
  const float* Wg    = (const float*)d_in[8];
  const float* bg    = (const float*)d_in[9];
  const float* gamma = (const float*)d_in[10];
  const float* beta  = (const float*)d_in[11];
  float* ws  = (float*)d_ws;
  float* out = (float*)d_out;

  // zero den accumulators + map + barrier flags (contiguous region)
  hipMemsetAsync(ws + OFF_DEN, 0,
                 ((size_t)Tc * Bc + 256 + 256 * 16) * sizeof(float), stream);

  hipLaunchKernelGGL(k_gemm, dim3(4096), dim3(256), 0, stream,
                     cs, Wk, bk, We, be, Ww, bw, Wg, bg, ws, out);
  hipLaunchKernelGGL(k_knorm, dim3(2048), dim3(256), 0, stream, ws + OFF_KN);
  hipLaunchKernelGGL(k_main, dim3(NBLK), dim3(NT), 0, stream,
                     cs, mem, gamma, beta, ws, out);
}